// Round 16
// baseline (75.288 us; speedup 1.0000x reference)
//
#include <hip/hip_runtime.h>
#include <hip/hip_bf16.h>

#define SEQ 1024

typedef __attribute__((ext_vector_type(8))) short s16x8;
typedef __attribute__((ext_vector_type(4))) float f32x4;
typedef __attribute__((ext_vector_type(2))) unsigned int u32x2;
typedef __attribute__((ext_vector_type(4))) unsigned int u32x4;
typedef __attribute__((ext_vector_type(2))) float f32x2;

// bf16 element offsets in workspace
//  G[j][v][512]; G[0] has b1 folded in (incl. v=38 pad row -> b1); v=38 zero for j>0
#define GT  0
#define W2P (5 * 39 * 512)
#define W3P (W2P + 256 * 512)
#define W4P (W3P + 64 * 512)

#define F2 (16 * 16)
#define F3 (8 * 8)
#define F4 (3 * 4)
#define FTOT (F2 + F3 + F4)

__device__ __forceinline__ unsigned int f2bf(float f) {
    unsigned int u = __float_as_uint(f);
    return (u + 0x7fffu + ((u >> 16) & 1u)) >> 16;   // RNE
}

__device__ __forceinline__ unsigned short bfbits(float f) {
    __hip_bfloat16 h = __float2bfloat16(f);
    unsigned short u;
    __builtin_memcpy(&u, &h, 2);
    return u;
}

__device__ __forceinline__ unsigned pk2(float a, float b) {
    return (unsigned)bfbits(a) | ((unsigned)bfbits(b) << 16);
}

__device__ __forceinline__ float bf2f(short x) {
    return __uint_as_float(((unsigned)(unsigned short)x) << 16);
}

__device__ __forceinline__ void cvt8(const s16x8 g, f32x2 o[4]) {
    #pragma unroll
    for (int h = 0; h < 4; ++h) {
        o[h][0] = bf2f(g[2 * h]);
        o[h][1] = bf2f(g[2 * h + 1]);
    }
}

// prep: blocks [0,195) -> bf16 G[j][v][o] (b1 folded into j==0); blocks [195,..) pack W2/3/4
__global__ void prep(const float* __restrict__ w1, const float* __restrict__ w2,
                     const float* __restrict__ w3, const float* __restrict__ w4,
                     const float* __restrict__ emb, const float* __restrict__ b1,
                     unsigned short* __restrict__ dst) {
    if (blockIdx.x < 195) {
        const int j = blockIdx.x / 39;
        const int v = blockIdx.x % 39;
        const int o = threadIdx.x;               // 0..511
        if (v >= 38) {
            dst[GT + (j * 39 + v) * 512 + o] = (j == 0) ? bfbits(b1[o]) : (unsigned short)0;
            return;
        }
        __shared__ float ev[128];
        if (threadIdx.x < 128) ev[threadIdx.x] = emb[v * 128 + threadIdx.x];
        __syncthreads();
        const float* wr = w1 + o * 640 + j * 128;
        float s = (j == 0) ? b1[o] : 0.f;
        #pragma unroll
        for (int e = 0; e < 128; e += 4) {
            const float4 a = *reinterpret_cast<const float4*>(wr + e);
            s += a.x * ev[e] + a.y * ev[e + 1] + a.z * ev[e + 2] + a.w * ev[e + 3];
        }
        dst[GT + (j * 39 + v) * 512 + o] = bfbits(s);
    } else {
        const int g = (blockIdx.x - 195) * 512 + threadIdx.x;
        if (g >= FTOT * 64) return;
        const int lane = g & 63;
        const int t    = g >> 6;
        const float* w; int K, N, KC, base, tl;
        if (t < F2)           { w = w2; K = 512; N = 256; KC = 16; base = W2P; tl = t; }
        else if (t < F2 + F3) { w = w3; K = 256; N = 128; KC = 8;  base = W3P; tl = t - F2; }
        else                  { w = w4; K = 128; N = 38;  KC = 4;  base = W4P; tl = t - F2 - F3; }
        const int ct  = tl / KC;
        const int kc  = tl - ct * KC;
        const int col = ct * 16 + (lane & 15);
        const int k0  = kc * 32 + (lane >> 4) * 8;
        unsigned short o8[8];
        #pragma unroll
        for (int e = 0; e < 8; ++e)
            o8[e] = (col < N) ? (unsigned short)f2bf(w[col * K + k0 + e]) : (unsigned short)0;
        *reinterpret_cast<s16x8*>(dst + base + (size_t)(tl * 64 + lane) * 8) =
            *reinterpret_cast<s16x8*>(o8);
    }
}

// LDS (48 KB, 512 threads, M=64):
//   q-buf0 @ 0     (16384): h1 quarter (64 rows x 128 dims, stride 256B)
//   q-buf1 @ 16384 (16384)
//   h2 overwrites [0,32768) after GEMM2 (64 x 256, stride 512B)
//   h3 @ 32768 (16384): 64 x 128, stride 256B
#define QB0 0
#define QB1 16384
#define H2S 0
#define H3S 32768

#define SWZ(b, row) ((b) ^ (((row) & 15) << 4))

__device__ __forceinline__ u32x2 pack_relu(f32x4 a, float4 b) {
    u32x2 r;
    r[0] = pk2(fmaxf(a[0] + b.x, 0.f), fmaxf(a[1] + b.y, 0.f));
    r[1] = pk2(fmaxf(a[2] + b.z, 0.f), fmaxf(a[3] + b.w, 0.f));
    return r;
}

__launch_bounds__(512, 4)
__global__ void fused_mlp(const int* __restrict__ tok,
                          const unsigned short* __restrict__ wbf,
                          const float* __restrict__ b2,
                          const float* __restrict__ b3,
                          const float* __restrict__ b4,
                          float* __restrict__ out) {
    __shared__ char smem[49152];
    const int tid  = threadIdx.x;
    const int lane = tid & 63;
    const int wave = tid >> 6;                 // 0..7
    const int l15  = lane & 15;
    const int l4   = lane >> 4;                // 0..3
    const int r0   = blockIdx.x * 64;
    const int s0   = r0 & (SEQ - 1);
    const int bat  = r0 >> 10;

    // per-thread context tokens; OOB -> 38 (zero/b1 row)
    const int p1row = tid >> 3;                // 0..63
    const int p1c   = tid & 7;
    int goff[5];
    #pragma unroll
    for (int j = 0; j < 5; ++j) {
        const int sp = s0 - 2 + p1row + j;
        const int t  = (sp >= 0 && sp < SEQ) ? tok[bat * SEQ + sp] : 38;
        goff[j] = (j * 39 + t) * 512;
    }

    // ---- helpers (T14 split: gload issues, gsum consumes) ----
    auto gload = [&](int q, int c, s16x8 (&g)[5]) {
        const int d = q * 128 + (c * 8 + p1c) * 8;
        #pragma unroll
        for (int j = 0; j < 5; ++j)
            g[j] = *reinterpret_cast<const s16x8*>(wbf + GT + goff[j] + d);
    };
    auto gsum = [&](int c, const s16x8 (&g)[5], int buf) {
        f32x2 s[4];
        cvt8(g[0], s);
        #pragma unroll
        for (int j = 1; j < 5; ++j) {
            f32x2 t[4];
            cvt8(g[j], t);
            #pragma unroll
            for (int h = 0; h < 4; ++h) s[h] += t[h];
        }
        u32x4 wv;
        #pragma unroll
        for (int h = 0; h < 4; ++h)
            wv[h] = pk2(fmaxf(s[h][0], 0.f), fmaxf(s[h][1], 0.f));
        *reinterpret_cast<u32x4*>(
            smem + buf + SWZ(p1row * 256 + (c * 8 + p1c) * 16, p1row)) = wv;
    };

    f32x4 acc2[4][2];                          // GEMM2 accumulator, carried across quarters
    #pragma unroll
    for (int rt = 0; rt < 4; ++rt)
        #pragma unroll
        for (int ct = 0; ct < 2; ++ct) acc2[rt][ct] = (f32x4){0.f, 0.f, 0.f, 0.f};

    auto ldxv = [&](int buf, int ks, s16x8 (&xv)[4]) {
        #pragma unroll
        for (int rt = 0; rt < 4; ++rt) {
            const int row = rt * 16 + l15;
            xv[rt] = *reinterpret_cast<const s16x8*>(
                smem + buf + SWZ(row * 256 + ks * 64 + l4 * 16, row));
        }
    };
    auto wload = [&](int ct, int k) {
        return *reinterpret_cast<const s16x8*>(
            wbf + W2P + ((ct * 16 + k) * 64 + lane) * 8);
    };
    auto mfma8 = [&](const s16x8& w0, const s16x8& w1, const s16x8 (&xv)[4]) {
        __builtin_amdgcn_s_setprio(1);
        #pragma unroll
        for (int rt = 0; rt < 4; ++rt)
            acc2[rt][0] = __builtin_amdgcn_mfma_f32_16x16x32_bf16(w0, xv[rt], acc2[rt][0], 0, 0, 0);
        #pragma unroll
        for (int rt = 0; rt < 4; ++rt)
            acc2[rt][1] = __builtin_amdgcn_mfma_f32_16x16x32_bf16(w1, xv[rt], acc2[rt][1], 0, 0, 0);
        __builtin_amdgcn_s_setprio(0);
    };

    // fused quarter step: consume quarter q (bufR), produce quarter qn (bufW).
    // Load order is crafted for in-order vmcnt: W2 loads precede G loads in each
    // stage so MFMA's wait on W2 leaves the G gathers in flight under the MFMAs.
    auto qstep = [&](int q, int bufR, int qn, int bufW, bool prod) {
        const int ct0 = wave * 2, ct1 = ct0 + 1;
        s16x8 gc0[5], gc1[5];
        s16x8 w00 = wload(ct0, q * 4 + 0), w10 = wload(ct1, q * 4 + 0);
        s16x8 w01 = wload(ct0, q * 4 + 1), w11 = wload(ct1, q * 4 + 1);
        if (prod) gload(qn, 0, gc0);
        s16x8 xv[4];
        ldxv(bufR, 0, xv); mfma8(w00, w10, xv);
        if (prod) gload(qn, 1, gc1);
        ldxv(bufR, 1, xv); mfma8(w01, w11, xv);
        s16x8 w02 = wload(ct0, q * 4 + 2), w12 = wload(ct1, q * 4 + 2);
        s16x8 w03 = wload(ct0, q * 4 + 3), w13 = wload(ct1, q * 4 + 3);
        ldxv(bufR, 2, xv); mfma8(w02, w12, xv);
        if (prod) gsum(0, gc0, bufW);
        ldxv(bufR, 3, xv); mfma8(w03, w13, xv);
        if (prod) gsum(1, gc1, bufW);
    };

    // ---------- prologue: produce quarter 0
    {
        s16x8 g0[5], g1[5];
        gload(0, 0, g0);
        gload(0, 1, g1);
        gsum(0, g0, QB0);
        gsum(1, g1, QB0);
    }
    __syncthreads();
    qstep(0, QB0, 1, QB1, true);
    __syncthreads();
    qstep(1, QB1, 2, QB0, true);
    __syncthreads();
    qstep(2, QB0, 3, QB1, true);
    __syncthreads();
    qstep(3, QB1, 0, QB0, false);
    __syncthreads();                           // all h1 reads done; [0,32K) free

    // ---------- h2 epilogue -> [0,32K), stride 512
    #pragma unroll
    for (int ct = 0; ct < 2; ++ct) {
        const int col0 = (wave * 2 + ct) * 16 + l4 * 4;
        const float4 bb = *reinterpret_cast<const float4*>(b2 + col0);
        #pragma unroll
        for (int rt = 0; rt < 4; ++rt) {
            const int row = rt * 16 + l15;
            *reinterpret_cast<u32x2*>(smem + H2S + SWZ(row * 512 + col0 * 2, row)) =
                pack_relu(acc2[rt][ct], bb);
        }
    }
    __syncthreads();

    // ---------- GEMM3: [64,256] -> [64,128]; wave=ct, 4 row-tiles; h3 -> [32K,48K)
    {
        f32x4 acc[4];
        #pragma unroll
        for (int rt = 0; rt < 4; ++rt) acc[rt] = (f32x4){0.f, 0.f, 0.f, 0.f};
        for (int ks = 0; ks < 8; ++ks) {
            const s16x8 w = *reinterpret_cast<const s16x8*>(
                wbf + W3P + ((wave * 8 + ks) * 64 + lane) * 8);
            s16x8 xv[4];
            #pragma unroll
            for (int rt = 0; rt < 4; ++rt) {
                const int row = rt * 16 + l15;
                xv[rt] = *reinterpret_cast<const s16x8*>(
                    smem + H2S + SWZ(row * 512 + ks * 64 + l4 * 16, row));
            }
            __builtin_amdgcn_s_setprio(1);
            #pragma unroll
            for (int rt = 0; rt < 4; ++rt)
                acc[rt] = __builtin_amdgcn_mfma_f32_16x16x32_bf16(w, xv[rt], acc[rt], 0, 0, 0);
            __builtin_amdgcn_s_setprio(0);
        }
        const int col0 = wave * 16 + l4 * 4;
        const float4 bb = *reinterpret_cast<const float4*>(b3 + col0);
        #pragma unroll
        for (int rt = 0; rt < 4; ++rt) {
            const int row = rt * 16 + l15;
            *reinterpret_cast<u32x2*>(smem + H3S + SWZ(row * 256 + col0 * 2, row)) =
                pack_relu(acc[rt], bb);
        }
    }
    __syncthreads();

    // ---------- GEMM4: [64,128] -> out[64,38]; 12 tasks over 8 waves
    for (int task = wave; task < 12; task += 8) {
        const int mt = task >> 2;
        const int rt = task & 3;
        f32x4 acc = (f32x4){0.f, 0.f, 0.f, 0.f};
        #pragma unroll
        for (int ks = 0; ks < 4; ++ks) {
            const int row = rt * 16 + l15;
            const s16x8 xv = *reinterpret_cast<const s16x8*>(
                smem + H3S + SWZ(row * 256 + ks * 64 + l4 * 16, row));
            const s16x8 w = *reinterpret_cast<const s16x8*>(
                wbf + W4P + ((mt * 4 + ks) * 64 + lane) * 8);
            acc = __builtin_amdgcn_mfma_f32_16x16x32_bf16(w, xv, acc, 0, 0, 0);
        }
        const int rg   = r0 + rt * 16 + l15;
        const int col0 = mt * 16 + l4 * 4;
        #pragma unroll
        for (int h = 0; h < 2; ++h) {
            const int c = col0 + 2 * h;
            if (c < 38) {
                f32x2 v;
                v[0] = acc[2 * h]     + b4[c];
                v[1] = acc[2 * h + 1] + b4[c + 1];
                *reinterpret_cast<f32x2*>(out + rg * 38 + c) = v;
            }
        }
    }
}

extern "C" void kernel_launch(void* const* d_in, const int* in_sizes, int n_in,
                              void* d_out, int out_size, void* d_ws, size_t ws_size,
                              hipStream_t stream) {
    const int*   tok = (const int*)d_in[0];
    const float* emb = (const float*)d_in[1];
    const float* W1  = (const float*)d_in[2];
    const float* b1  = (const float*)d_in[3];
    const float* W2  = (const float*)d_in[4];
    const float* b2  = (const float*)d_in[5];
    const float* W3  = (const float*)d_in[6];
    const float* b3  = (const float*)d_in[7];
    const float* W4  = (const float*)d_in[8];
    const float* b4  = (const float*)d_in[9];
    float* out = (float*)d_out;
    unsigned short* wbf = (unsigned short*)d_ws;

    const int pack_blocks = (FTOT * 64 + 511) / 512;     // 42
    prep<<<195 + pack_blocks, 512, 0, stream>>>(W1, W2, W3, W4, emb, b1, wbf);
    fused_mlp<<<1024, 512, 0, stream>>>(tok, wbf, b2, b3, b4, out);
}

// Round 17
// 75.244 us; speedup vs baseline: 1.0006x; 1.0006x over previous
//
#include <hip/hip_runtime.h>
#include <hip/hip_bf16.h>

#define SEQ 1024

typedef __attribute__((ext_vector_type(8))) short s16x8;
typedef __attribute__((ext_vector_type(4))) float f32x4;
typedef __attribute__((ext_vector_type(2))) unsigned int u32x2;
typedef __attribute__((ext_vector_type(4))) unsigned int u32x4;
typedef __attribute__((ext_vector_type(2))) float f32x2;

// bf16 element offsets in workspace
//  G[j][v][512]; G[0] has b1 folded in (incl. v=38 pad row -> b1); v=38 zero for j>0
#define GT  0
#define W2P (5 * 39 * 512)
#define W3P (W2P + 256 * 512)
#define W4P (W3P + 64 * 512)

#define F2 (16 * 16)
#define F3 (8 * 8)
#define F4 (3 * 4)
#define FTOT (F2 + F3 + F4)

__device__ __forceinline__ unsigned int f2bf(float f) {
    unsigned int u = __float_as_uint(f);
    return (u + 0x7fffu + ((u >> 16) & 1u)) >> 16;   // RNE
}

__device__ __forceinline__ unsigned short bfbits(float f) {
    __hip_bfloat16 h = __float2bfloat16(f);
    unsigned short u;
    __builtin_memcpy(&u, &h, 2);
    return u;
}

__device__ __forceinline__ unsigned pk2(float a, float b) {
    return (unsigned)bfbits(a) | ((unsigned)bfbits(b) << 16);
}

__device__ __forceinline__ float bf2f(short x) {
    return __uint_as_float(((unsigned)(unsigned short)x) << 16);
}

__device__ __forceinline__ void cvt8(const s16x8 g, f32x2 o[4]) {
    #pragma unroll
    for (int h = 0; h < 4; ++h) {
        o[h][0] = bf2f(g[2 * h]);
        o[h][1] = bf2f(g[2 * h + 1]);
    }
}

// prep: blocks [0,195) -> bf16 G[j][v][o] (b1 folded into j==0); blocks [195,..) pack W2/3/4
__global__ void prep(const float* __restrict__ w1, const float* __restrict__ w2,
                     const float* __restrict__ w3, const float* __restrict__ w4,
                     const float* __restrict__ emb, const float* __restrict__ b1,
                     unsigned short* __restrict__ dst) {
    if (blockIdx.x < 195) {
        const int j = blockIdx.x / 39;
        const int v = blockIdx.x % 39;
        const int o = threadIdx.x;               // 0..511
        if (v >= 38) {
            dst[GT + (j * 39 + v) * 512 + o] = (j == 0) ? bfbits(b1[o]) : (unsigned short)0;
            return;
        }
        __shared__ float ev[128];
        if (threadIdx.x < 128) ev[threadIdx.x] = emb[v * 128 + threadIdx.x];
        __syncthreads();
        const float* wr = w1 + o * 640 + j * 128;
        float s = (j == 0) ? b1[o] : 0.f;
        #pragma unroll
        for (int e = 0; e < 128; e += 4) {
            const float4 a = *reinterpret_cast<const float4*>(wr + e);
            s += a.x * ev[e] + a.y * ev[e + 1] + a.z * ev[e + 2] + a.w * ev[e + 3];
        }
        dst[GT + (j * 39 + v) * 512 + o] = bfbits(s);
    } else {
        const int g = (blockIdx.x - 195) * 512 + threadIdx.x;
        if (g >= FTOT * 64) return;
        const int lane = g & 63;
        const int t    = g >> 6;
        const float* w; int K, N, KC, base, tl;
        if (t < F2)           { w = w2; K = 512; N = 256; KC = 16; base = W2P; tl = t; }
        else if (t < F2 + F3) { w = w3; K = 256; N = 128; KC = 8;  base = W3P; tl = t - F2; }
        else                  { w = w4; K = 128; N = 38;  KC = 4;  base = W4P; tl = t - F2 - F3; }
        const int ct  = tl / KC;
        const int kc  = tl - ct * KC;
        const int col = ct * 16 + (lane & 15);
        const int k0  = kc * 32 + (lane >> 4) * 8;
        unsigned short o8[8];
        #pragma unroll
        for (int e = 0; e < 8; ++e)
            o8[e] = (col < N) ? (unsigned short)f2bf(w[col * K + k0 + e]) : (unsigned short)0;
        *reinterpret_cast<s16x8*>(dst + base + (size_t)(tl * 64 + lane) * 8) =
            *reinterpret_cast<s16x8*>(o8);
    }
}

// LDS padded to 56 KB (2 blocks/CU -> compiler targets 4 waves/SIMD -> VGPR cap 128;
// 48 KB would invite a 3-block occupancy target with VGPR 64 -> spills, per R16):
//   q-buf0 @ 0     (16384): h1 quarter (64 rows x 128 dims, stride 256B)
//   q-buf1 @ 16384 (16384)
//   h2 overwrites [0,32768) after GEMM2 (64 x 256, stride 512B)
//   h3 @ 32768 (16384): 64 x 128, stride 256B
//   [49152,57344) dead padding
#define QB0 0
#define QB1 16384
#define H2S 0
#define H3S 32768

#define SWZ(b, row) ((b) ^ (((row) & 15) << 4))

__device__ __forceinline__ u32x2 pack_relu(f32x4 a, float4 b) {
    u32x2 r;
    r[0] = pk2(fmaxf(a[0] + b.x, 0.f), fmaxf(a[1] + b.y, 0.f));
    r[1] = pk2(fmaxf(a[2] + b.z, 0.f), fmaxf(a[3] + b.w, 0.f));
    return r;
}

__launch_bounds__(512, 4)
__global__ void fused_mlp(const int* __restrict__ tok,
                          const unsigned short* __restrict__ wbf,
                          const float* __restrict__ b2,
                          const float* __restrict__ b3,
                          const float* __restrict__ b4,
                          float* __restrict__ out) {
    __shared__ char smem[57344];
    const int tid  = threadIdx.x;
    const int lane = tid & 63;
    const int wave = tid >> 6;                 // 0..7
    const int l15  = lane & 15;
    const int l4   = lane >> 4;                // 0..3
    const int r0   = blockIdx.x * 64;
    const int s0   = r0 & (SEQ - 1);
    const int bat  = r0 >> 10;

    // per-thread context tokens; OOB -> 38 (zero/b1 row)
    const int p1row = tid >> 3;                // 0..63
    const int p1c   = tid & 7;
    int goff[5];
    #pragma unroll
    for (int j = 0; j < 5; ++j) {
        const int sp = s0 - 2 + p1row + j;
        const int t  = (sp >= 0 && sp < SEQ) ? tok[bat * SEQ + sp] : 38;
        goff[j] = (j * 39 + t) * 512;
    }

    // ---- helpers (T14 split: gload issues, gsum consumes) ----
    auto gload = [&](int q, int c, s16x8 (&g)[5]) {
        const int d = q * 128 + (c * 8 + p1c) * 8;
        #pragma unroll
        for (int j = 0; j < 5; ++j)
            g[j] = *reinterpret_cast<const s16x8*>(wbf + GT + goff[j] + d);
    };
    auto gsum = [&](int c, const s16x8 (&g)[5], int buf) {
        f32x2 s[4];
        cvt8(g[0], s);
        #pragma unroll
        for (int j = 1; j < 5; ++j) {
            f32x2 t[4];
            cvt8(g[j], t);
            #pragma unroll
            for (int h = 0; h < 4; ++h) s[h] += t[h];
        }
        u32x4 wv;
        #pragma unroll
        for (int h = 0; h < 4; ++h)
            wv[h] = pk2(fmaxf(s[h][0], 0.f), fmaxf(s[h][1], 0.f));
        *reinterpret_cast<u32x4*>(
            smem + buf + SWZ(p1row * 256 + (c * 8 + p1c) * 16, p1row)) = wv;
    };

    f32x4 acc2[4][2];                          // GEMM2 accumulator, carried across quarters
    #pragma unroll
    for (int rt = 0; rt < 4; ++rt)
        #pragma unroll
        for (int ct = 0; ct < 2; ++ct) acc2[rt][ct] = (f32x4){0.f, 0.f, 0.f, 0.f};

    auto ldxv = [&](int buf, int ks, s16x8 (&xv)[4]) {
        #pragma unroll
        for (int rt = 0; rt < 4; ++rt) {
            const int row = rt * 16 + l15;
            xv[rt] = *reinterpret_cast<const s16x8*>(
                smem + buf + SWZ(row * 256 + ks * 64 + l4 * 16, row));
        }
    };
    auto wload = [&](int ct, int k) {
        return *reinterpret_cast<const s16x8*>(
            wbf + W2P + ((ct * 16 + k) * 64 + lane) * 8);
    };
    auto mfma8 = [&](const s16x8& w0, const s16x8& w1, const s16x8 (&xv)[4]) {
        __builtin_amdgcn_s_setprio(1);
        #pragma unroll
        for (int rt = 0; rt < 4; ++rt)
            acc2[rt][0] = __builtin_amdgcn_mfma_f32_16x16x32_bf16(w0, xv[rt], acc2[rt][0], 0, 0, 0);
        #pragma unroll
        for (int rt = 0; rt < 4; ++rt)
            acc2[rt][1] = __builtin_amdgcn_mfma_f32_16x16x32_bf16(w1, xv[rt], acc2[rt][1], 0, 0, 0);
        __builtin_amdgcn_s_setprio(0);
    };

    // fused quarter step: consume quarter q (bufR), produce quarter qn (bufW).
    // W2 loads precede G loads per stage so the MFMA's vmcnt wait on W2 leaves
    // the G gathers in flight under the MFMAs (in-order VMEM completion).
    auto qstep = [&](int q, int bufR, int qn, int bufW, bool prod) {
        const int ct0 = wave * 2, ct1 = ct0 + 1;
        s16x8 gc0[5], gc1[5];
        s16x8 w00 = wload(ct0, q * 4 + 0), w10 = wload(ct1, q * 4 + 0);
        s16x8 w01 = wload(ct0, q * 4 + 1), w11 = wload(ct1, q * 4 + 1);
        if (prod) gload(qn, 0, gc0);
        s16x8 xv[4];
        ldxv(bufR, 0, xv); mfma8(w00, w10, xv);
        if (prod) gload(qn, 1, gc1);
        ldxv(bufR, 1, xv); mfma8(w01, w11, xv);
        s16x8 w02 = wload(ct0, q * 4 + 2), w12 = wload(ct1, q * 4 + 2);
        s16x8 w03 = wload(ct0, q * 4 + 3), w13 = wload(ct1, q * 4 + 3);
        ldxv(bufR, 2, xv); mfma8(w02, w12, xv);
        if (prod) gsum(0, gc0, bufW);
        ldxv(bufR, 3, xv); mfma8(w03, w13, xv);
        if (prod) gsum(1, gc1, bufW);
    };

    // ---------- prologue: produce quarter 0
    {
        s16x8 g0[5], g1[5];
        gload(0, 0, g0);
        gload(0, 1, g1);
        gsum(0, g0, QB0);
        gsum(1, g1, QB0);
    }
    __syncthreads();
    qstep(0, QB0, 1, QB1, true);
    __syncthreads();
    qstep(1, QB1, 2, QB0, true);
    __syncthreads();
    qstep(2, QB0, 3, QB1, true);
    __syncthreads();
    qstep(3, QB1, 0, QB0, false);
    __syncthreads();                           // all h1 reads done; [0,32K) free

    // ---------- h2 epilogue -> [0,32K), stride 512
    #pragma unroll
    for (int ct = 0; ct < 2; ++ct) {
        const int col0 = (wave * 2 + ct) * 16 + l4 * 4;
        const float4 bb = *reinterpret_cast<const float4*>(b2 + col0);
        #pragma unroll
        for (int rt = 0; rt < 4; ++rt) {
            const int row = rt * 16 + l15;
            *reinterpret_cast<u32x2*>(smem + H2S + SWZ(row * 512 + col0 * 2, row)) =
                pack_relu(acc2[rt][ct], bb);
        }
    }
    __syncthreads();

    // ---------- GEMM3: [64,256] -> [64,128]; wave=ct, 4 row-tiles; h3 -> [32K,48K)
    {
        f32x4 acc[4];
        #pragma unroll
        for (int rt = 0; rt < 4; ++rt) acc[rt] = (f32x4){0.f, 0.f, 0.f, 0.f};
        for (int ks = 0; ks < 8; ++ks) {
            const s16x8 w = *reinterpret_cast<const s16x8*>(
                wbf + W3P + ((wave * 8 + ks) * 64 + lane) * 8);
            s16x8 xv[4];
            #pragma unroll
            for (int rt = 0; rt < 4; ++rt) {
                const int row = rt * 16 + l15;
                xv[rt] = *reinterpret_cast<const s16x8*>(
                    smem + H2S + SWZ(row * 512 + ks * 64 + l4 * 16, row));
            }
            __builtin_amdgcn_s_setprio(1);
            #pragma unroll
            for (int rt = 0; rt < 4; ++rt)
                acc[rt] = __builtin_amdgcn_mfma_f32_16x16x32_bf16(w, xv[rt], acc[rt], 0, 0, 0);
            __builtin_amdgcn_s_setprio(0);
        }
        const int col0 = wave * 16 + l4 * 4;
        const float4 bb = *reinterpret_cast<const float4*>(b3 + col0);
        #pragma unroll
        for (int rt = 0; rt < 4; ++rt) {
            const int row = rt * 16 + l15;
            *reinterpret_cast<u32x2*>(smem + H3S + SWZ(row * 256 + col0 * 2, row)) =
                pack_relu(acc[rt], bb);
        }
    }
    __syncthreads();

    // ---------- GEMM4: [64,128] -> out[64,38]; 12 tasks over 8 waves
    for (int task = wave; task < 12; task += 8) {
        const int mt = task >> 2;
        const int rt = task & 3;
        f32x4 acc = (f32x4){0.f, 0.f, 0.f, 0.f};
        #pragma unroll
        for (int ks = 0; ks < 4; ++ks) {
            const int row = rt * 16 + l15;
            const s16x8 xv = *reinterpret_cast<const s16x8*>(
                smem + H3S + SWZ(row * 256 + ks * 64 + l4 * 16, row));
            const s16x8 w = *reinterpret_cast<const s16x8*>(
                wbf + W4P + ((mt * 4 + ks) * 64 + lane) * 8);
            acc = __builtin_amdgcn_mfma_f32_16x16x32_bf16(w, xv, acc, 0, 0, 0);
        }
        const int rg   = r0 + rt * 16 + l15;
        const int col0 = mt * 16 + l4 * 4;
        #pragma unroll
        for (int h = 0; h < 2; ++h) {
            const int c = col0 + 2 * h;
            if (c < 38) {
                f32x2 v;
                v[0] = acc[2 * h]     + b4[c];
                v[1] = acc[2 * h + 1] + b4[c + 1];
                *reinterpret_cast<f32x2*>(out + rg * 38 + c) = v;
            }
        }
    }
}

extern "C" void kernel_launch(void* const* d_in, const int* in_sizes, int n_in,
                              void* d_out, int out_size, void* d_ws, size_t ws_size,
                              hipStream_t stream) {
    const int*   tok = (const int*)d_in[0];
    const float* emb = (const float*)d_in[1];
    const float* W1  = (const float*)d_in[2];
    const float* b1  = (const float*)d_in[3];
    const float* W2  = (const float*)d_in[4];
    const float* b2  = (const float*)d_in[5];
    const float* W3  = (const float*)d_in[6];
    const float* b3  = (const float*)d_in[7];
    const float* W4  = (const float*)d_in[8];
    const float* b4  = (const float*)d_in[9];
    float* out = (float*)d_out;
    unsigned short* wbf = (unsigned short*)d_ws;

    const int pack_blocks = (FTOT * 64 + 511) / 512;     // 42
    prep<<<195 + pack_blocks, 512, 0, stream>>>(W1, W2, W3, W4, emb, b1, wbf);
    fused_mlp<<<1024, 512, 0, stream>>>(tok, wbf, b2, b3, b4, out);
}

// Round 18
// 50.032 us; speedup vs baseline: 1.5048x; 1.5039x over previous
//
#include <hip/hip_runtime.h>
#include <hip/hip_bf16.h>

#define SEQ 1024

typedef __attribute__((ext_vector_type(8))) short s16x8;
typedef __attribute__((ext_vector_type(4))) float f32x4;
typedef __attribute__((ext_vector_type(2))) unsigned int u32x2;
typedef __attribute__((ext_vector_type(4))) unsigned int u32x4;
typedef __attribute__((ext_vector_type(2))) float f32x2;

// bf16 element offsets in workspace
//  G[j][v][512]; G[0] has b1 folded in (incl. v=38 pad row -> b1); v=38 zero for j>0
#define GT  0
#define W2P (5 * 39 * 512)
#define W3P (W2P + 256 * 512)
#define W4P (W3P + 64 * 512)

#define F2 (16 * 16)
#define F3 (8 * 8)
#define F4 (3 * 4)
#define FTOT (F2 + F3 + F4)

__device__ __forceinline__ unsigned int f2bf(float f) {
    unsigned int u = __float_as_uint(f);
    return (u + 0x7fffu + ((u >> 16) & 1u)) >> 16;   // RNE
}

__device__ __forceinline__ unsigned short bfbits(float f) {
    __hip_bfloat16 h = __float2bfloat16(f);
    unsigned short u;
    __builtin_memcpy(&u, &h, 2);
    return u;
}

__device__ __forceinline__ unsigned pk2(float a, float b) {
    return (unsigned)bfbits(a) | ((unsigned)bfbits(b) << 16);
}

__device__ __forceinline__ float bf2f(short x) {
    return __uint_as_float(((unsigned)(unsigned short)x) << 16);
}

__device__ __forceinline__ void cvt8(const s16x8 g, f32x2 o[4]) {
    #pragma unroll
    for (int h = 0; h < 4; ++h) {
        o[h][0] = bf2f(g[2 * h]);
        o[h][1] = bf2f(g[2 * h + 1]);
    }
}

// prep: blocks [0,195) -> bf16 G[j][v][o] (b1 folded into j==0); blocks [195,..) pack W2/3/4
__global__ void prep(const float* __restrict__ w1, const float* __restrict__ w2,
                     const float* __restrict__ w3, const float* __restrict__ w4,
                     const float* __restrict__ emb, const float* __restrict__ b1,
                     unsigned short* __restrict__ dst) {
    if (blockIdx.x < 195) {
        const int j = blockIdx.x / 39;
        const int v = blockIdx.x % 39;
        const int o = threadIdx.x;               // 0..511
        if (v >= 38) {
            dst[GT + (j * 39 + v) * 512 + o] = (j == 0) ? bfbits(b1[o]) : (unsigned short)0;
            return;
        }
        __shared__ float ev[128];
        if (threadIdx.x < 128) ev[threadIdx.x] = emb[v * 128 + threadIdx.x];
        __syncthreads();
        const float* wr = w1 + o * 640 + j * 128;
        float s = (j == 0) ? b1[o] : 0.f;
        #pragma unroll
        for (int e = 0; e < 128; e += 4) {
            const float4 a = *reinterpret_cast<const float4*>(wr + e);
            s += a.x * ev[e] + a.y * ev[e + 1] + a.z * ev[e + 2] + a.w * ev[e + 3];
        }
        dst[GT + (j * 39 + v) * 512 + o] = bfbits(s);
    } else {
        const int g = (blockIdx.x - 195) * 512 + threadIdx.x;
        if (g >= FTOT * 64) return;
        const int lane = g & 63;
        const int t    = g >> 6;
        const float* w; int K, N, KC, base, tl;
        if (t < F2)           { w = w2; K = 512; N = 256; KC = 16; base = W2P; tl = t; }
        else if (t < F2 + F3) { w = w3; K = 256; N = 128; KC = 8;  base = W3P; tl = t - F2; }
        else                  { w = w4; K = 128; N = 38;  KC = 4;  base = W4P; tl = t - F2 - F3; }
        const int ct  = tl / KC;
        const int kc  = tl - ct * KC;
        const int col = ct * 16 + (lane & 15);
        const int k0  = kc * 32 + (lane >> 4) * 8;
        unsigned short o8[8];
        #pragma unroll
        for (int e = 0; e < 8; ++e)
            o8[e] = (col < N) ? (unsigned short)f2bf(w[col * K + k0 + e]) : (unsigned short)0;
        *reinterpret_cast<s16x8*>(dst + base + (size_t)(tl * 64 + lane) * 8) =
            *reinterpret_cast<s16x8*>(o8);
    }
}

// LDS (48 KB, 512 threads, M=64):
//   q-buf0 @ 0     (16384): h1 quarter (64 rows x 128 dims, stride 256B)
//   q-buf1 @ 16384 (16384)
//   h2 overwrites [0,32768) after GEMM2 (64 x 256, stride 512B)
//   h3 @ 32768 (16384): 64 x 128, stride 256B
#define QB0 0
#define QB1 16384
#define H2S 0
#define H3S 32768

#define SWZ(b, row) ((b) ^ (((row) & 15) << 4))

__device__ __forceinline__ u32x2 pack_relu(f32x4 a, float4 b) {
    u32x2 r;
    r[0] = pk2(fmaxf(a[0] + b.x, 0.f), fmaxf(a[1] + b.y, 0.f));
    r[1] = pk2(fmaxf(a[2] + b.z, 0.f), fmaxf(a[3] + b.w, 0.f));
    return r;
}

__launch_bounds__(512, 4)
__global__ void fused_mlp(const int* __restrict__ tok,
                          const unsigned short* __restrict__ wbf,
                          const float* __restrict__ b2,
                          const float* __restrict__ b3,
                          const float* __restrict__ b4,
                          float* __restrict__ out) {
    __shared__ char smem[49152];
    const int tid  = threadIdx.x;
    const int lane = tid & 63;
    const int wave = tid >> 6;                 // 0..7
    const int l15  = lane & 15;
    const int l4   = lane >> 4;                // 0..3
    const int r0   = blockIdx.x * 64;
    const int s0   = r0 & (SEQ - 1);
    const int bat  = r0 >> 10;

    // per-thread context tokens; OOB -> 38 (zero/b1 row)
    const int p1row = tid >> 3;                // 0..63
    const int p1c   = tid & 7;
    int goff[5];
    #pragma unroll
    for (int j = 0; j < 5; ++j) {
        const int sp = s0 - 2 + p1row + j;
        const int t  = (sp >= 0 && sp < SEQ) ? tok[bat * SEQ + sp] : 38;
        goff[j] = (j * 39 + t) * 512;
    }

    // ---- helpers (T14 split: gload issues, gsum consumes) ----
    auto gload = [&](int q, int c, s16x8 (&g)[5]) {
        const int d = q * 128 + (c * 8 + p1c) * 8;
        #pragma unroll
        for (int j = 0; j < 5; ++j)
            g[j] = *reinterpret_cast<const s16x8*>(wbf + GT + goff[j] + d);
    };
    auto gsum = [&](int c, const s16x8 (&g)[5], int buf) {
        f32x2 s[4];
        cvt8(g[0], s);
        #pragma unroll
        for (int j = 1; j < 5; ++j) {
            f32x2 t[4];
            cvt8(g[j], t);
            #pragma unroll
            for (int h = 0; h < 4; ++h) s[h] += t[h];
        }
        u32x4 wv;
        #pragma unroll
        for (int h = 0; h < 4; ++h)
            wv[h] = pk2(fmaxf(s[h][0], 0.f), fmaxf(s[h][1], 0.f));
        *reinterpret_cast<u32x4*>(
            smem + buf + SWZ(p1row * 256 + (c * 8 + p1c) * 16, p1row)) = wv;
    };

    f32x4 acc2[4][2];                          // GEMM2 accumulator, carried across quarters
    #pragma unroll
    for (int rt = 0; rt < 4; ++rt)
        #pragma unroll
        for (int ct = 0; ct < 2; ++ct) acc2[rt][ct] = (f32x4){0.f, 0.f, 0.f, 0.f};

    auto ldxv = [&](int buf, int ks, s16x8 (&xv)[4]) {
        #pragma unroll
        for (int rt = 0; rt < 4; ++rt) {
            const int row = rt * 16 + l15;
            xv[rt] = *reinterpret_cast<const s16x8*>(
                smem + buf + SWZ(row * 256 + ks * 64 + l4 * 16, row));
        }
    };
    auto wload = [&](int ct, int k) {
        return *reinterpret_cast<const s16x8*>(
            wbf + W2P + ((ct * 16 + k) * 64 + lane) * 8);
    };
    auto mfma8 = [&](const s16x8& w0, const s16x8& w1, const s16x8 (&xv)[4]) {
        __builtin_amdgcn_s_setprio(1);
        #pragma unroll
        for (int rt = 0; rt < 4; ++rt)
            acc2[rt][0] = __builtin_amdgcn_mfma_f32_16x16x32_bf16(w0, xv[rt], acc2[rt][0], 0, 0, 0);
        #pragma unroll
        for (int rt = 0; rt < 4; ++rt)
            acc2[rt][1] = __builtin_amdgcn_mfma_f32_16x16x32_bf16(w1, xv[rt], acc2[rt][1], 0, 0, 0);
        __builtin_amdgcn_s_setprio(0);
    };

    // quarter step, register-budgeted (R18): only ONE 5-load G chunk in flight at
    // a time (gA dies at gsum before gB is born), W loaded one pair per stage.
    // W pair issued BEFORE the G chunk in its stage, so the MFMA's vmcnt wait on
    // W leaves the G gathers outstanding under the MFMA + LDS work.
    auto qstep = [&](int q, int bufR, int qn, int bufW, bool prod) {
        const int ct0 = wave * 2, ct1 = ct0 + 1;
        s16x8 xv[4];
        s16x8 gA[5], gB[5];
        // stage 0: W(ks0) -> gA -> mfma(ks0)   [wait W only; gA in flight]
        s16x8 w00 = wload(ct0, q * 4 + 0), w10 = wload(ct1, q * 4 + 0);
        if (prod) gload(qn, 0, gA);
        ldxv(bufR, 0, xv); mfma8(w00, w10, xv);
        // stage 1: W(ks1) -> mfma(ks1) [drains gA] -> consume gA
        s16x8 w01 = wload(ct0, q * 4 + 1), w11 = wload(ct1, q * 4 + 1);
        ldxv(bufR, 1, xv); mfma8(w01, w11, xv);
        if (prod) gsum(0, gA, bufW);
        // stage 2: W(ks2) -> gB -> mfma(ks2)   [wait W only; gB in flight]
        s16x8 w02 = wload(ct0, q * 4 + 2), w12 = wload(ct1, q * 4 + 2);
        if (prod) gload(qn, 1, gB);
        ldxv(bufR, 2, xv); mfma8(w02, w12, xv);
        // stage 3: W(ks3) -> mfma(ks3) [drains gB] -> consume gB
        s16x8 w03 = wload(ct0, q * 4 + 3), w13 = wload(ct1, q * 4 + 3);
        ldxv(bufR, 3, xv); mfma8(w03, w13, xv);
        if (prod) gsum(1, gB, bufW);
    };

    // ---------- prologue: produce quarter 0
    {
        s16x8 g0[5], g1[5];
        gload(0, 0, g0);
        gload(0, 1, g1);
        gsum(0, g0, QB0);
        gsum(1, g1, QB0);
    }
    __syncthreads();
    qstep(0, QB0, 1, QB1, true);
    __syncthreads();
    qstep(1, QB1, 2, QB0, true);
    __syncthreads();
    qstep(2, QB0, 3, QB1, true);
    __syncthreads();
    qstep(3, QB1, 0, QB0, false);
    __syncthreads();                           // all h1 reads done; [0,32K) free

    // ---------- h2 epilogue -> [0,32K), stride 512
    #pragma unroll
    for (int ct = 0; ct < 2; ++ct) {
        const int col0 = (wave * 2 + ct) * 16 + l4 * 4;
        const float4 bb = *reinterpret_cast<const float4*>(b2 + col0);
        #pragma unroll
        for (int rt = 0; rt < 4; ++rt) {
            const int row = rt * 16 + l15;
            *reinterpret_cast<u32x2*>(smem + H2S + SWZ(row * 512 + col0 * 2, row)) =
                pack_relu(acc2[rt][ct], bb);
        }
    }
    __syncthreads();

    // ---------- GEMM3: [64,256] -> [64,128]; wave=ct, 4 row-tiles; h3 -> [32K,48K)
    {
        f32x4 acc[4];
        #pragma unroll
        for (int rt = 0; rt < 4; ++rt) acc[rt] = (f32x4){0.f, 0.f, 0.f, 0.f};
        for (int ks = 0; ks < 8; ++ks) {
            const s16x8 w = *reinterpret_cast<const s16x8*>(
                wbf + W3P + ((wave * 8 + ks) * 64 + lane) * 8);
            s16x8 xv[4];
            #pragma unroll
            for (int rt = 0; rt < 4; ++rt) {
                const int row = rt * 16 + l15;
                xv[rt] = *reinterpret_cast<const s16x8*>(
                    smem + H2S + SWZ(row * 512 + ks * 64 + l4 * 16, row));
            }
            __builtin_amdgcn_s_setprio(1);
            #pragma unroll
            for (int rt = 0; rt < 4; ++rt)
                acc[rt] = __builtin_amdgcn_mfma_f32_16x16x32_bf16(w, xv[rt], acc[rt], 0, 0, 0);
            __builtin_amdgcn_s_setprio(0);
        }
        const int col0 = wave * 16 + l4 * 4;
        const float4 bb = *reinterpret_cast<const float4*>(b3 + col0);
        #pragma unroll
        for (int rt = 0; rt < 4; ++rt) {
            const int row = rt * 16 + l15;
            *reinterpret_cast<u32x2*>(smem + H3S + SWZ(row * 256 + col0 * 2, row)) =
                pack_relu(acc[rt], bb);
        }
    }
    __syncthreads();

    // ---------- GEMM4: [64,128] -> out[64,38]; 12 tasks over 8 waves
    for (int task = wave; task < 12; task += 8) {
        const int mt = task >> 2;
        const int rt = task & 3;
        f32x4 acc = (f32x4){0.f, 0.f, 0.f, 0.f};
        #pragma unroll
        for (int ks = 0; ks < 4; ++ks) {
            const int row = rt * 16 + l15;
            const s16x8 xv = *reinterpret_cast<const s16x8*>(
                smem + H3S + SWZ(row * 256 + ks * 64 + l4 * 16, row));
            const s16x8 w = *reinterpret_cast<const s16x8*>(
                wbf + W4P + ((mt * 4 + ks) * 64 + lane) * 8);
            acc = __builtin_amdgcn_mfma_f32_16x16x32_bf16(w, xv, acc, 0, 0, 0);
        }
        const int rg   = r0 + rt * 16 + l15;
        const int col0 = mt * 16 + l4 * 4;
        #pragma unroll
        for (int h = 0; h < 2; ++h) {
            const int c = col0 + 2 * h;
            if (c < 38) {
                f32x2 v;
                v[0] = acc[2 * h]     + b4[c];
                v[1] = acc[2 * h + 1] + b4[c + 1];
                *reinterpret_cast<f32x2*>(out + rg * 38 + c) = v;
            }
        }
    }
}

extern "C" void kernel_launch(void* const* d_in, const int* in_sizes, int n_in,
                              void* d_out, int out_size, void* d_ws, size_t ws_size,
                              hipStream_t stream) {
    const int*   tok = (const int*)d_in[0];
    const float* emb = (const float*)d_in[1];
    const float* W1  = (const float*)d_in[2];
    const float* b1  = (const float*)d_in[3];
    const float* W2  = (const float*)d_in[4];
    const float* b2  = (const float*)d_in[5];
    const float* W3  = (const float*)d_in[6];
    const float* b3  = (const float*)d_in[7];
    const float* W4  = (const float*)d_in[8];
    const float* b4  = (const float*)d_in[9];
    float* out = (float*)d_out;
    unsigned short* wbf = (unsigned short*)d_ws;

    const int pack_blocks = (FTOT * 64 + 511) / 512;     // 42
    prep<<<195 + pack_blocks, 512, 0, stream>>>(W1, W2, W3, W4, emb, b1, wbf);
    fused_mlp<<<1024, 512, 0, stream>>>(tok, wbf, b2, b3, b4, out);
}

// Round 19
// 48.916 us; speedup vs baseline: 1.5391x; 1.0228x over previous
//
#include <hip/hip_runtime.h>
#include <hip/hip_bf16.h>

#define SEQ 1024

typedef __attribute__((ext_vector_type(8))) short s16x8;
typedef __attribute__((ext_vector_type(4))) float f32x4;
typedef __attribute__((ext_vector_type(2))) unsigned int u32x2;
typedef __attribute__((ext_vector_type(4))) unsigned int u32x4;
typedef __attribute__((ext_vector_type(2))) float f32x2;

// bf16 element offsets in workspace
//  G[j][v][512]; G[0] has b1 folded in (incl. v=38 pad row -> b1); v=38 zero for j>0
#define GT  0
#define W2P (5 * 39 * 512)
#define W3P (W2P + 256 * 512)
#define W4P (W3P + 64 * 512)

#define F2 (16 * 16)
#define F3 (8 * 8)
#define F4 (3 * 4)
#define FTOT (F2 + F3 + F4)

__device__ __forceinline__ unsigned int f2bf(float f) {
    unsigned int u = __float_as_uint(f);
    return (u + 0x7fffu + ((u >> 16) & 1u)) >> 16;   // RNE
}

__device__ __forceinline__ unsigned short bfbits(float f) {
    __hip_bfloat16 h = __float2bfloat16(f);
    unsigned short u;
    __builtin_memcpy(&u, &h, 2);
    return u;
}

__device__ __forceinline__ unsigned pk2(float a, float b) {
    return (unsigned)bfbits(a) | ((unsigned)bfbits(b) << 16);
}

__device__ __forceinline__ float bf2f(short x) {
    return __uint_as_float(((unsigned)(unsigned short)x) << 16);
}

// unpack s16x8 (8 bf16) into 4 f32x2 pairs
__device__ __forceinline__ void cvt8(const s16x8 g, f32x2 o[4]) {
    #pragma unroll
    for (int h = 0; h < 4; ++h) {
        o[h][0] = bf2f(g[2 * h]);
        o[h][1] = bf2f(g[2 * h + 1]);
    }
}

// prep: blocks [0,195) -> bf16 G[j][v][o] (b1 folded into j==0); blocks [195,..) pack W2/3/4
__global__ void prep(const float* __restrict__ w1, const float* __restrict__ w2,
                     const float* __restrict__ w3, const float* __restrict__ w4,
                     const float* __restrict__ emb, const float* __restrict__ b1,
                     unsigned short* __restrict__ dst) {
    if (blockIdx.x < 195) {
        const int j = blockIdx.x / 39;
        const int v = blockIdx.x % 39;
        const int o = threadIdx.x;               // 0..511
        if (v >= 38) {                           // pad row: b1 for j==0, else 0
            dst[GT + (j * 39 + v) * 512 + o] = (j == 0) ? bfbits(b1[o]) : (unsigned short)0;
            return;
        }
        __shared__ float ev[128];
        if (threadIdx.x < 128) ev[threadIdx.x] = emb[v * 128 + threadIdx.x];
        __syncthreads();
        const float* wr = w1 + o * 640 + j * 128;
        float s = (j == 0) ? b1[o] : 0.f;
        #pragma unroll
        for (int e = 0; e < 128; e += 4) {
            const float4 a = *reinterpret_cast<const float4*>(wr + e);
            s += a.x * ev[e] + a.y * ev[e + 1] + a.z * ev[e + 2] + a.w * ev[e + 3];
        }
        dst[GT + (j * 39 + v) * 512 + o] = bfbits(s);
    } else {
        const int g = (blockIdx.x - 195) * 512 + threadIdx.x;
        if (g >= FTOT * 64) return;
        const int lane = g & 63;
        const int t    = g >> 6;
        const float* w; int K, N, KC, base, tl;
        if (t < F2)           { w = w2; K = 512; N = 256; KC = 16; base = W2P; tl = t; }
        else if (t < F2 + F3) { w = w3; K = 256; N = 128; KC = 8;  base = W3P; tl = t - F2; }
        else                  { w = w4; K = 128; N = 38;  KC = 4;  base = W4P; tl = t - F2 - F3; }
        const int ct  = tl / KC;
        const int kc  = tl - ct * KC;
        const int col = ct * 16 + (lane & 15);
        const int k0  = kc * 32 + (lane >> 4) * 8;
        unsigned short o8[8];
        #pragma unroll
        for (int e = 0; e < 8; ++e)
            o8[e] = (col < N) ? (unsigned short)f2bf(w[col * K + k0 + e]) : (unsigned short)0;
        *reinterpret_cast<s16x8*>(dst + base + (size_t)(tl * 64 + lane) * 8) =
            *reinterpret_cast<s16x8*>(o8);
    }
}

// LDS (64 KB, 512 threads, M=64, 2 blocks/CU):
//   buf A @ 0     (32768): h1 dims [0,256)   -> h2 (64 x 256, stride 512B)
//   buf B @ 32768 (32768): h1 dims [256,512) -> h3 (64 x 128, stride 256B)
#define BA 0
#define BB 32768

#define SWZ(b, row) ((b) ^ (((row) & 15) << 4))

__device__ __forceinline__ u32x2 pack_relu(f32x4 a, float4 b) {
    u32x2 r;
    r[0] = pk2(fmaxf(a[0] + b.x, 0.f), fmaxf(a[1] + b.y, 0.f));
    r[1] = pk2(fmaxf(a[2] + b.z, 0.f), fmaxf(a[3] + b.w, 0.f));
    return r;
}

__launch_bounds__(512, 4)
__global__ void fused_mlp(const int* __restrict__ tok,
                          const unsigned short* __restrict__ wbf,
                          const float* __restrict__ b2,
                          const float* __restrict__ b3,
                          const float* __restrict__ b4,
                          float* __restrict__ out) {
    __shared__ char smem[65536];
    const int tid  = threadIdx.x;
    const int lane = tid & 63;
    const int wave = tid >> 6;                 // 0..7
    const int l15  = lane & 15;
    const int l4   = lane >> 4;                // 0..3
    const int r0   = blockIdx.x * 64;
    const int s0   = r0 & (SEQ - 1);
    const int bat  = r0 >> 10;

    // per-thread context tokens (8 threads/row share -> L1 broadcast); OOB -> 38
    const int p1row = tid >> 3;                // 0..63
    const int p1c   = tid & 7;
    int goff[5];
    #pragma unroll
    for (int j = 0; j < 5; ++j) {
        const int sp = s0 - 2 + p1row + j;
        const int t  = (sp >= 0 && sp < SEQ) ? tok[bat * SEQ + sp] : 38;
        goff[j] = (j * 39 + t) * 512;
    }

    // ---------- phase 1a: h1 dims [0,256) = relu(sum_j G[j][t_j]) -> buf A (b1 in G0)
    #pragma unroll
    for (int it = 0; it < 4; ++it) {
        const int c8 = it * 8 + p1c;           // 0..31
        const int d  = c8 * 8;
        s16x8 g[5];
        #pragma unroll
        for (int j = 0; j < 5; ++j)
            g[j] = *reinterpret_cast<const s16x8*>(wbf + GT + goff[j] + d);
        f32x2 s[4];
        cvt8(g[0], s);
        #pragma unroll
        for (int j = 1; j < 5; ++j) {
            f32x2 t[4];
            cvt8(g[j], t);
            #pragma unroll
            for (int h = 0; h < 4; ++h) s[h] += t[h];
        }
        u32x4 wv;
        #pragma unroll
        for (int h = 0; h < 4; ++h)
            wv[h] = pk2(fmaxf(s[h][0], 0.f), fmaxf(s[h][1], 0.f));
        *reinterpret_cast<u32x4*>(smem + BA + SWZ(p1row * 512 + c8 * 16, p1row)) = wv;
    }
    __syncthreads();

    // ---------- GEMM2 part A (ks 0..7 from buf A) + phase 1b (dims [256,512) -> buf B)
    f32x4 acc2[4][2];
    #pragma unroll
    for (int rt = 0; rt < 4; ++rt)
        #pragma unroll
        for (int ct = 0; ct < 2; ++ct) acc2[rt][ct] = (f32x4){0.f, 0.f, 0.f, 0.f};
    {
        #pragma unroll
        for (int it = 0; it < 4; ++it) {
            const int c8 = it * 8 + p1c;
            const int d  = 256 + c8 * 8;
            s16x8 g[5];
            #pragma unroll
            for (int j = 0; j < 5; ++j)
                g[j] = *reinterpret_cast<const s16x8*>(wbf + GT + goff[j] + d);
            f32x2 s[4];
            cvt8(g[0], s);
            #pragma unroll
            for (int j = 1; j < 5; ++j) {
                f32x2 t[4];
                cvt8(g[j], t);
                #pragma unroll
                for (int h = 0; h < 4; ++h) s[h] += t[h];
            }
            u32x4 wv;
            #pragma unroll
            for (int h = 0; h < 4; ++h)
                wv[h] = pk2(fmaxf(s[h][0], 0.f), fmaxf(s[h][1], 0.f));
            *reinterpret_cast<u32x4*>(smem + BB + SWZ(p1row * 512 + c8 * 16, p1row)) = wv;
        }
        for (int ks = 0; ks < 8; ++ks) {
            s16x8 xv[4];
            #pragma unroll
            for (int rt = 0; rt < 4; ++rt) {
                const int row = rt * 16 + l15;
                xv[rt] = *reinterpret_cast<const s16x8*>(
                    smem + BA + SWZ(row * 512 + ks * 64 + l4 * 16, row));
            }
            __builtin_amdgcn_s_setprio(1);
            #pragma unroll
            for (int ct = 0; ct < 2; ++ct) {
                const s16x8 w = *reinterpret_cast<const s16x8*>(
                    wbf + W2P + (((wave * 2 + ct) * 16 + ks) * 64 + lane) * 8);
                #pragma unroll
                for (int rt = 0; rt < 4; ++rt)
                    acc2[rt][ct] = __builtin_amdgcn_mfma_f32_16x16x32_bf16(w, xv[rt], acc2[rt][ct], 0, 0, 0);
            }
            __builtin_amdgcn_s_setprio(0);
        }
    }
    __syncthreads();

    // ---------- GEMM2 part B (ks 8..15 from buf B) + epilogue -> h2 in buf A
    {
        for (int ks = 0; ks < 8; ++ks) {
            s16x8 xv[4];
            #pragma unroll
            for (int rt = 0; rt < 4; ++rt) {
                const int row = rt * 16 + l15;
                xv[rt] = *reinterpret_cast<const s16x8*>(
                    smem + BB + SWZ(row * 512 + ks * 64 + l4 * 16, row));
            }
            __builtin_amdgcn_s_setprio(1);
            #pragma unroll
            for (int ct = 0; ct < 2; ++ct) {
                const s16x8 w = *reinterpret_cast<const s16x8*>(
                    wbf + W2P + (((wave * 2 + ct) * 16 + 8 + ks) * 64 + lane) * 8);
                #pragma unroll
                for (int rt = 0; rt < 4; ++rt)
                    acc2[rt][ct] = __builtin_amdgcn_mfma_f32_16x16x32_bf16(w, xv[rt], acc2[rt][ct], 0, 0, 0);
            }
            __builtin_amdgcn_s_setprio(0);
        }
        #pragma unroll
        for (int ct = 0; ct < 2; ++ct) {
            const int col0 = (wave * 2 + ct) * 16 + l4 * 4;
            const float4 bb = *reinterpret_cast<const float4*>(b2 + col0);
            #pragma unroll
            for (int rt = 0; rt < 4; ++rt) {
                const int row = rt * 16 + l15;
                *reinterpret_cast<u32x2*>(smem + BA + SWZ(row * 512 + col0 * 2, row)) =
                    pack_relu(acc2[rt][ct], bb);
            }
        }
    }
    __syncthreads();

    // ---------- GEMM3: [64,256] -> [64,128]; wave=ct, 4 row-tiles; h3 -> buf B
    {
        f32x4 acc[4];
        #pragma unroll
        for (int rt = 0; rt < 4; ++rt) acc[rt] = (f32x4){0.f, 0.f, 0.f, 0.f};
        for (int ks = 0; ks < 8; ++ks) {
            const s16x8 w = *reinterpret_cast<const s16x8*>(
                wbf + W3P + ((wave * 8 + ks) * 64 + lane) * 8);
            s16x8 xv[4];
            #pragma unroll
            for (int rt = 0; rt < 4; ++rt) {
                const int row = rt * 16 + l15;
                xv[rt] = *reinterpret_cast<const s16x8*>(
                    smem + BA + SWZ(row * 512 + ks * 64 + l4 * 16, row));
            }
            __builtin_amdgcn_s_setprio(1);
            #pragma unroll
            for (int rt = 0; rt < 4; ++rt)
                acc[rt] = __builtin_amdgcn_mfma_f32_16x16x32_bf16(w, xv[rt], acc[rt], 0, 0, 0);
            __builtin_amdgcn_s_setprio(0);
        }
        const int col0 = wave * 16 + l4 * 4;
        const float4 bb = *reinterpret_cast<const float4*>(b3 + col0);
        #pragma unroll
        for (int rt = 0; rt < 4; ++rt) {
            const int row = rt * 16 + l15;
            *reinterpret_cast<u32x2*>(smem + BB + SWZ(row * 256 + col0 * 2, row)) =
                pack_relu(acc[rt], bb);
        }
    }
    __syncthreads();

    // ---------- GEMM4: [64,128] -> out[64,38]; 12 tasks over 8 waves
    for (int task = wave; task < 12; task += 8) {
        const int mt = task >> 2;
        const int rt = task & 3;
        f32x4 acc = (f32x4){0.f, 0.f, 0.f, 0.f};
        #pragma unroll
        for (int ks = 0; ks < 4; ++ks) {
            const int row = rt * 16 + l15;
            const s16x8 xv = *reinterpret_cast<const s16x8*>(
                smem + BB + SWZ(row * 256 + ks * 64 + l4 * 16, row));
            const s16x8 w = *reinterpret_cast<const s16x8*>(
                wbf + W4P + ((mt * 4 + ks) * 64 + lane) * 8);
            acc = __builtin_amdgcn_mfma_f32_16x16x32_bf16(w, xv, acc, 0, 0, 0);
        }
        const int rg   = r0 + rt * 16 + l15;
        const int col0 = mt * 16 + l4 * 4;
        #pragma unroll
        for (int h = 0; h < 2; ++h) {
            const int c = col0 + 2 * h;
            if (c < 38) {
                f32x2 v;
                v[0] = acc[2 * h]     + b4[c];
                v[1] = acc[2 * h + 1] + b4[c + 1];
                *reinterpret_cast<f32x2*>(out + rg * 38 + c) = v;
            }
        }
    }
}

extern "C" void kernel_launch(void* const* d_in, const int* in_sizes, int n_in,
                              void* d_out, int out_size, void* d_ws, size_t ws_size,
                              hipStream_t stream) {
    const int*   tok = (const int*)d_in[0];
    const float* emb = (const float*)d_in[1];
    const float* W1  = (const float*)d_in[2];
    const float* b1  = (const float*)d_in[3];
    const float* W2  = (const float*)d_in[4];
    const float* b2  = (const float*)d_in[5];
    const float* W3  = (const float*)d_in[6];
    const float* b3  = (const float*)d_in[7];
    const float* W4  = (const float*)d_in[8];
    const float* b4  = (const float*)d_in[9];
    float* out = (float*)d_out;
    unsigned short* wbf = (unsigned short*)d_ws;

    const int pack_blocks = (FTOT * 64 + 511) / 512;     // 42
    prep<<<195 + pack_blocks, 512, 0, stream>>>(W1, W2, W3, W4, emb, b1, wbf);
    fused_mlp<<<1024, 512, 0, stream>>>(tok, wbf, b2, b3, b4, out);
}